// Round 7
// baseline (1902.320 us; speedup 1.0000x reference)
//
#include <hip/hip_runtime.h>

// SparseMatrixEquivariantLayer on MI355X.
// Decomposition:
//   memset ws accumulators
//   kA: per-(entry,feature-PAIR) packed v2f32 atomics -> sum_row, sum_col, Dsum;
//       scalar atomics for cnt_row/cnt_col; block partials for pa.
//       Packed atomics halve the atomic op count vs scalar-per-feature (the
//       scalar kA was atomic-op-throughput-bound at ~173 G ops/s, 14.7% HBM BW).
//   kN: per-node matvecs -> row_b, col_b, diag_b; block partials for pd
//   kS: reduce partials, compute const_all = all_scalar+bias0, const_diag = diag_scalar+bias1
//   kB: per-entry Y = vals@W0 + row_b[r] + col_b[c] + const_all + dm*(diag_b[r]+const_diag)
//   kC: transpose scatter: Y[tout] += vals[tin]@W1, 8 lanes/entry, packed v2f32
//       atomics so the 16 floats of one entry land as 8 pk ops on ONE 64B line.
//
// Packed atomic path: HIP's unsafeAtomicAdd(float2*, float2) lowers to
// global_atomic_pk_add_f32 (no-return) on gfx90a+. SFINAE-dispatched: if the
// float2 overload is absent in this ROCm, falls back to two scalar atomicAdds
// (correct, = old baseline). No inline asm -> compiler tracks vmcnt itself.

#define NNODES 100000
#define DF 16
#define NBLKA 2048

// --- packed f32x2 atomic add with compile-time fallback ---------------------
template <typename P>
__device__ __forceinline__ auto pk_add_impl(P* p, float2 v, int)
    -> decltype(unsafeAtomicAdd(p, v), void())
{
    (void)unsafeAtomicAdd(p, v);           // global_atomic_pk_add_f32
}

template <typename P>
__device__ __forceinline__ void pk_add_impl(P* p, float2 v, long)
{
    float* f = reinterpret_cast<float*>(p); // fallback: 2 scalar atomics
    atomicAdd(f + 0, v.x);
    atomicAdd(f + 1, v.y);
}

__device__ __forceinline__ void pk_atomic_add(float* addr, float x, float y)
{
    float2 v = make_float2(x, y);
    pk_add_impl(reinterpret_cast<float2*>(addr), v, 0);  // int pref -> packed if well-formed
}
// ----------------------------------------------------------------------------

__global__ __launch_bounds__(256) void kA(
    const float* __restrict__ vals, const int* __restrict__ row,
    const int* __restrict__ col, int nnz,
    float* __restrict__ sum_row, float* __restrict__ sum_col,
    float* __restrict__ Dsum, float* __restrict__ cnt_row,
    float* __restrict__ cnt_col, float* __restrict__ pa_part)
{
    const long long total = (long long)nnz * 8;       // feature PAIRS
    const int fp = threadIdx.x & 7;                   // feature pair index 0..7
    const long long stride = (long long)gridDim.x * blockDim.x;  // multiple of 8
    float pax = 0.f, pay = 0.f;
    for (long long pos = (long long)blockIdx.x * blockDim.x + threadIdx.x;
         pos < total; pos += stride) {
        int e = (int)(pos >> 3);
        float2 v = ((const float2*)vals)[pos];        // 8B/lane, coalesced
        int r = row[e];
        int c = col[e];
        pax += v.x; pay += v.y;
        pk_atomic_add(&sum_row[(size_t)r * DF + 2 * fp], v.x, v.y);
        pk_atomic_add(&sum_col[(size_t)c * DF + 2 * fp], v.x, v.y);
        if (r == c) pk_atomic_add(&Dsum[(size_t)r * DF + 2 * fp], v.x, v.y);
        if (fp == 0) {
            atomicAdd(&cnt_row[r], 1.f);
            atomicAdd(&cnt_col[c], 1.f);
        }
    }
    __shared__ float redx[256], redy[256];
    redx[threadIdx.x] = pax;
    redy[threadIdx.x] = pay;
    __syncthreads();
    if (threadIdx.x < 16) {
        int f = threadIdx.x;
        int fpair = f >> 1, comp = f & 1;
        float s = 0.f;
        for (int k = fpair; k < 256; k += 8) s += comp ? redy[k] : redx[k];
        pa_part[blockIdx.x * DF + f] = s;
    }
}

__global__ __launch_bounds__(256) void kN(
    const float* __restrict__ W,
    const float* __restrict__ sum_row, const float* __restrict__ sum_col,
    const float* __restrict__ Dsum, const float* __restrict__ cnt_row,
    const float* __restrict__ cnt_col,
    float* __restrict__ row_b, float* __restrict__ col_b,
    float* __restrict__ diag_b, float* __restrict__ pd_part, int n)
{
    // stage W2..W10 (9 x 16x16) into LDS; sw[(k-2)*256 + i*16 + j]
    __shared__ float sw[9 * 256];
    __shared__ float spd[16];
    for (int i = threadIdx.x; i < 9 * 256; i += blockDim.x) sw[i] = W[2 * 256 + i];
    if (threadIdx.x < 16) spd[threadIdx.x] = 0.f;
    __syncthreads();

    int node = blockIdx.x * blockDim.x + threadIdx.x;
    float D[16];
    if (node < n) {
        float Pr[16], Pc[16];
        float cr = fmaxf(cnt_row[node], 1.f);
        float cc = fmaxf(cnt_col[node], 1.f);
        float icr = 1.f / cr, icc = 1.f / cc;
        #pragma unroll
        for (int i = 0; i < 16; ++i) {
            D[i]  = Dsum[(size_t)node * DF + i];
            Pr[i] = sum_row[(size_t)node * DF + i] * icr;
            Pc[i] = sum_col[(size_t)node * DF + i] * icc;
        }
        #pragma unroll
        for (int j = 0; j < 16; ++j) {
            float db = 0.f, rb = 0.f, cb = 0.f;
            #pragma unroll
            for (int i = 0; i < 16; ++i) {
                float Di = D[i], Pri = Pr[i], Pci = Pc[i];
                db = fmaf(Di,  sw[0 * 256 + i * 16 + j], db);  // W2
                rb = fmaf(Di,  sw[1 * 256 + i * 16 + j], rb);  // W3
                cb = fmaf(Di,  sw[2 * 256 + i * 16 + j], cb);  // W4
                db = fmaf(Pri, sw[3 * 256 + i * 16 + j], db);  // W5
                rb = fmaf(Pri, sw[4 * 256 + i * 16 + j], rb);  // W6
                cb = fmaf(Pri, sw[5 * 256 + i * 16 + j], cb);  // W7
                db = fmaf(Pci, sw[6 * 256 + i * 16 + j], db);  // W8
                rb = fmaf(Pci, sw[7 * 256 + i * 16 + j], rb);  // W9
                cb = fmaf(Pci, sw[8 * 256 + i * 16 + j], cb);  // W10
            }
            diag_b[(size_t)node * DF + j] = db;
            row_b[(size_t)node * DF + j]  = rb;
            col_b[(size_t)node * DF + j]  = cb;
        }
        #pragma unroll
        for (int i = 0; i < 16; ++i) atomicAdd(&spd[i], D[i]);
    }
    __syncthreads();
    if (threadIdx.x < 16) pd_part[blockIdx.x * DF + threadIdx.x] = spd[threadIdx.x];
}

__global__ __launch_bounds__(256) void kS(
    const float* __restrict__ W, const float* __restrict__ bias,
    const float* __restrict__ pa_part, int nblka,
    const float* __restrict__ pd_part, int nblkn,
    float inv_nnz, float inv_n, float* __restrict__ cst)
{
    __shared__ float red[256];
    __shared__ float pa[16], pd[16];
    int t = threadIdx.x;
    int f = t & 15, g = t >> 4;
    float s = 0.f;
    for (int b = g; b < nblka; b += 16) s += pa_part[b * DF + f];
    red[t] = s;
    __syncthreads();
    if (t < 16) {
        float a = 0.f;
        for (int k = t; k < 256; k += 16) a += red[k];
        pa[t] = a * inv_nnz;
    }
    __syncthreads();
    s = 0.f;
    for (int b = g; b < nblkn; b += 16) s += pd_part[b * DF + f];
    red[t] = s;
    __syncthreads();
    if (t < 16) {
        float a = 0.f;
        for (int k = t; k < 256; k += 16) a += red[k];
        pd[t] = a * inv_n;
    }
    __syncthreads();
    if (t < 16) {
        float ds = 0.f, as = 0.f;
        #pragma unroll
        for (int i = 0; i < 16; ++i) {
            float pdi = pd[i], pai = pa[i];
            ds = fmaf(pdi, W[11 * 256 + i * 16 + t], ds);
            ds = fmaf(pai, W[13 * 256 + i * 16 + t], ds);
            as = fmaf(pdi, W[12 * 256 + i * 16 + t], as);
            as = fmaf(pai, W[14 * 256 + i * 16 + t], as);
        }
        cst[t]      = as + bias[t];       // const_all = all_scalar + bias0
        cst[16 + t] = ds + bias[16 + t];  // const_diag = diag_scalar + bias1
    }
}

__global__ __launch_bounds__(256) void kB(
    const float* __restrict__ vals, const int* __restrict__ row,
    const int* __restrict__ col, const float* __restrict__ W,
    const float* __restrict__ row_b, const float* __restrict__ col_b,
    const float* __restrict__ diag_b, const float* __restrict__ cst,
    float* __restrict__ out, int nnz)
{
    __shared__ float w0[256];
    __shared__ float scst[32];
    w0[threadIdx.x] = W[threadIdx.x];
    if (threadIdx.x < 32) scst[threadIdx.x] = cst[threadIdx.x];
    __syncthreads();

    int e = blockIdx.x * blockDim.x + threadIdx.x;
    if (e >= nnz) return;

    const float4* vp = (const float4*)(vals + (size_t)e * DF);
    float4 q0 = vp[0], q1 = vp[1], q2 = vp[2], q3 = vp[3];
    float v[16] = {q0.x, q0.y, q0.z, q0.w, q1.x, q1.y, q1.z, q1.w,
                   q2.x, q2.y, q2.z, q2.w, q3.x, q3.y, q3.z, q3.w};
    int r = row[e], c = col[e];

    float acc[16];
    const float4* rb = (const float4*)(row_b + (size_t)r * DF);
    const float4* cb = (const float4*)(col_b + (size_t)c * DF);
    #pragma unroll
    for (int k = 0; k < 4; ++k) {
        float4 a = rb[k], b = cb[k];
        acc[4 * k + 0] = scst[4 * k + 0] + a.x + b.x;
        acc[4 * k + 1] = scst[4 * k + 1] + a.y + b.y;
        acc[4 * k + 2] = scst[4 * k + 2] + a.z + b.z;
        acc[4 * k + 3] = scst[4 * k + 3] + a.w + b.w;
    }
    if (r == c) {
        const float4* db = (const float4*)(diag_b + (size_t)r * DF);
        #pragma unroll
        for (int k = 0; k < 4; ++k) {
            float4 d = db[k];
            acc[4 * k + 0] += d.x + scst[16 + 4 * k + 0];
            acc[4 * k + 1] += d.y + scst[16 + 4 * k + 1];
            acc[4 * k + 2] += d.z + scst[16 + 4 * k + 2];
            acc[4 * k + 3] += d.w + scst[16 + 4 * k + 3];
        }
    }
    #pragma unroll
    for (int i = 0; i < 16; ++i) {
        float vi = v[i];
        #pragma unroll
        for (int j = 0; j < 16; ++j) acc[j] = fmaf(vi, w0[i * 16 + j], acc[j]);
    }
    float4* op = (float4*)(out + (size_t)e * DF);
    op[0] = make_float4(acc[0], acc[1], acc[2], acc[3]);
    op[1] = make_float4(acc[4], acc[5], acc[6], acc[7]);
    op[2] = make_float4(acc[8], acc[9], acc[10], acc[11]);
    op[3] = make_float4(acc[12], acc[13], acc[14], acc[15]);
}

// 8 lanes per transpose-entry: lane j2 computes feature pair (2*j2, 2*j2+1);
// the 8 packed atomics of one entry land contiguously on one 64B line.
__global__ __launch_bounds__(256) void kC(
    const float* __restrict__ vals, const int* __restrict__ tin,
    const int* __restrict__ tout, const float* __restrict__ W,
    float* __restrict__ out, int nnzt)
{
    __shared__ float w1[256];
    for (int i = threadIdx.x; i < 256; i += blockDim.x) w1[i] = W[256 + i];
    __syncthreads();

    int gid = blockIdx.x * blockDim.x + threadIdx.x;
    int t = gid >> 3;   // transpose-entry index
    int j2 = gid & 7;   // feature pair index
    if (t >= nnzt) return;
    int ei = tin[t], eo = tout[t];

    float2 v = ((const float2*)vals)[(size_t)ei * 8 + j2];  // 8 lanes -> one 64B line
    float acc0 = 0.f, acc1 = 0.f;
    #pragma unroll
    for (int i = 0; i < 16; ++i) {
        float vi = __shfl((i & 1) ? v.y : v.x, i >> 1, 8);  // broadcast v_i in 8-lane group
        acc0 = fmaf(vi, w1[i * 16 + 2 * j2 + 0], acc0);
        acc1 = fmaf(vi, w1[i * 16 + 2 * j2 + 1], acc1);
    }
    pk_atomic_add(&out[(size_t)eo * DF + 2 * j2], acc0, acc1);
}

extern "C" void kernel_launch(void* const* d_in, const int* in_sizes, int n_in,
                              void* d_out, int out_size, void* d_ws, size_t ws_size,
                              hipStream_t stream)
{
    const float* vals    = (const float*)d_in[0];
    const float* weights = (const float*)d_in[1];
    const float* bias    = (const float*)d_in[2];
    const int*   row     = (const int*)d_in[3];
    const int*   col     = (const int*)d_in[4];
    const int*   tin     = (const int*)d_in[5];
    const int*   tout    = (const int*)d_in[6];

    const int nnz  = in_sizes[0] / DF;
    const int nnzt = in_sizes[5];
    const int n    = NNODES;
    const int nblkn = (n + 255) / 256;

    float* ws = (float*)d_ws;
    float* sum_row = ws;
    float* sum_col = sum_row + (size_t)n * DF;
    float* Dsum    = sum_col + (size_t)n * DF;
    float* cnt_row = Dsum + (size_t)n * DF;
    float* cnt_col = cnt_row + n;
    float* row_b   = cnt_col + n;
    float* col_b   = row_b + (size_t)n * DF;
    float* diag_b  = col_b + (size_t)n * DF;
    float* pa_part = diag_b + (size_t)n * DF;
    float* pd_part = pa_part + (size_t)NBLKA * DF;
    float* cst     = pd_part + (size_t)nblkn * DF;

    // zero the atomic-accumulation region: sum_row..cnt_col == n*50 floats
    hipMemsetAsync(ws, 0, (size_t)n * 50 * sizeof(float), stream);

    kA<<<NBLKA, 256, 0, stream>>>(vals, row, col, nnz, sum_row, sum_col, Dsum,
                                  cnt_row, cnt_col, pa_part);
    kN<<<nblkn, 256, 0, stream>>>(weights, sum_row, sum_col, Dsum, cnt_row,
                                  cnt_col, row_b, col_b, diag_b, pd_part, n);
    kS<<<1, 256, 0, stream>>>(weights, bias, pa_part, NBLKA, pd_part, nblkn,
                              1.f / (float)nnz, 1.f / (float)n, cst);
    kB<<<(nnz + 255) / 256, 256, 0, stream>>>(vals, row, col, weights, row_b,
                                              col_b, diag_b, cst, (float*)d_out, nnz);

    long long tthreads = (long long)nnzt * 8;
    kC<<<(int)((tthreads + 255) / 256), 256, 0, stream>>>(vals, tin, tout, weights,
                                                          (float*)d_out, nnzt);
}

// Round 9
// 1895.448 us; speedup vs baseline: 1.0036x; 1.0036x over previous
//
#include <hip/hip_runtime.h>

// SparseMatrixEquivariantLayer on MI355X.
//
// Round-7 finding: device-scope atomics write through to HBM (~64B per
// line-touch) and kA runs at the ~1.07 TB/s atomic write-through ceiling
// (scalar: 750MB/787us; packed pk_add: 1.25GB/1173us -> pk atomics emit TWO
// write events per touch, hence the regression). Fix: make the RMWs stay in
// the per-XCD L2:
//   - per-XCD accumulator replicas indexed by the HW XCC_ID register
//     (waves never migrate XCDs, so each replica is only ever touched
//     through its own L2 -> workgroup-scope atomics are sufficient)
//   - __hip_atomic_fetch_add with __HIP_MEMORY_SCOPE_WORKGROUP: executes the
//     RMW in the local L2, no memory-side write-through (global atomics
//     always run at >= L2; L1 has no atomic path, so cross-CU atomicity on
//     one XCD is preserved)
//   - 4 node-range passes so the per-XCD replica slice (13.6/4 = 3.4 MB)
//     fits the 4 MiB L2; non-temporal loads keep the streams from evicting it
//   - kernel-end writeback publishes replicas; kN sums the 8 replicas
// Fallback if ws_size can't hold the replicas: nrep=1 + device-scope atomics
// (= the proven 1523us baseline).
//
//   memset ws accumulators
//   kA2 x P: scatter sums/counts into per-XCD replicas (wg-scope atomics);
//            diag (rare) device-scope into shared Dsum; pa block partials
//   kN: sum replicas, per-node matvecs -> row_b, col_b, diag_b; pd partials
//   kS: reduce partials -> const_all, const_diag
//   kB: per-entry Y = vals@W0 + row_b[r] + col_b[c] + cst (+diag terms)
//   kC: transpose scatter, 16 lanes/entry so the 16 scalar atomics of one
//       entry land on ONE 64B line in one instruction (proven form).

#define NNODES 100000
#define DF 16
#define NBLKA 2048
#define NXCD 8

template<bool WG>
__device__ __forceinline__ void aadd(float* p, float v)
{
    if constexpr (WG)
        __hip_atomic_fetch_add(p, v, __ATOMIC_RELAXED, __HIP_MEMORY_SCOPE_WORKGROUP);
    else
        atomicAdd(p, v);
}

// rep layout per replica (stride 34*NNODES floats):
//   [sum_row n*16][sum_col n*16][cnt_row n][cnt_col n]
template<bool WG>
__global__ __launch_bounds__(256) void kA2(
    const float* __restrict__ vals, const int* __restrict__ row,
    const int* __restrict__ col, int nnz,
    float* __restrict__ rep, unsigned long long rep_stride,
    float* __restrict__ Dsum, float* __restrict__ pa_part,
    int lo, int hi)
{
    int xcc = 0;
    if constexpr (WG) {
        unsigned x;
        asm volatile("s_getreg_b32 %0, hwreg(HW_REG_XCC_ID)" : "=s"(x));
        xcc = (int)(x & 7u);
    }
    float* __restrict__ srow = rep + (size_t)xcc * rep_stride;
    float* __restrict__ scol = srow + (size_t)DF * NNODES;
    float* __restrict__ crow = srow + (size_t)2 * DF * NNODES;
    float* __restrict__ ccol = crow + NNODES;

    const long long total = (long long)nnz * DF;
    const int f = threadIdx.x & 15;
    const long long stride = (long long)gridDim.x * blockDim.x;  // mult of 16
    float pax = 0.f;
    for (long long pos = (long long)blockIdx.x * blockDim.x + threadIdx.x;
         pos < total; pos += stride) {
        int e = (int)(pos >> 4);
        int r = __builtin_nontemporal_load(&row[e]);
        int c = __builtin_nontemporal_load(&col[e]);
        bool rin = (r >= lo) && (r < hi);
        bool cin = (c >= lo) && (c < hi);
        float v = 0.f;
        if (rin || cin) v = __builtin_nontemporal_load(&vals[pos]);
        if (rin) {
            pax += v;                      // each entry counted in exactly one pass
            aadd<WG>(&srow[(size_t)r * DF + f], v);
            if (f == 0) aadd<WG>(&crow[r], 1.f);
            if (r == c) atomicAdd(&Dsum[(size_t)r * DF + f], v);  // rare: device scope
        }
        if (cin) {
            aadd<WG>(&scol[(size_t)c * DF + f], v);
            if (f == 0) aadd<WG>(&ccol[c], 1.f);
        }
    }
    __shared__ float red[256];
    red[threadIdx.x] = pax;
    __syncthreads();
    if (threadIdx.x < 16) {
        float s = 0.f;
        for (int k = threadIdx.x; k < 256; k += 16) s += red[k];
        pa_part[blockIdx.x * DF + threadIdx.x] += s;   // accumulate across passes
    }
}

__global__ __launch_bounds__(256) void kN(
    const float* __restrict__ W,
    const float* __restrict__ rep, unsigned long long rep_stride, int nrep,
    const float* __restrict__ Dsum,
    float* __restrict__ row_b, float* __restrict__ col_b,
    float* __restrict__ diag_b, float* __restrict__ pd_part, int n)
{
    // stage W2..W10 (9 x 16x16) into LDS; sw[(k-2)*256 + i*16 + j]
    __shared__ float sw[9 * 256];
    __shared__ float spd[16];
    for (int i = threadIdx.x; i < 9 * 256; i += blockDim.x) sw[i] = W[2 * 256 + i];
    if (threadIdx.x < 16) spd[threadIdx.x] = 0.f;
    __syncthreads();

    int node = blockIdx.x * blockDim.x + threadIdx.x;
    float D[16];
    if (node < n) {
        float Sr[16], Sc[16];
        #pragma unroll
        for (int i = 0; i < 16; ++i) { Sr[i] = 0.f; Sc[i] = 0.f; }
        float cr = 0.f, cc = 0.f;
        for (int x = 0; x < nrep; ++x) {
            const float* base = rep + (size_t)x * rep_stride;
            #pragma unroll
            for (int i = 0; i < 16; ++i) {
                Sr[i] += base[(size_t)node * DF + i];
                Sc[i] += base[(size_t)DF * NNODES + (size_t)node * DF + i];
            }
            cr += base[(size_t)2 * DF * NNODES + node];
            cc += base[(size_t)2 * DF * NNODES + NNODES + node];
        }
        float icr = 1.f / fmaxf(cr, 1.f);
        float icc = 1.f / fmaxf(cc, 1.f);
        float Pr[16], Pc[16];
        #pragma unroll
        for (int i = 0; i < 16; ++i) {
            D[i]  = Dsum[(size_t)node * DF + i];
            Pr[i] = Sr[i] * icr;
            Pc[i] = Sc[i] * icc;
        }
        #pragma unroll
        for (int j = 0; j < 16; ++j) {
            float db = 0.f, rb = 0.f, cb = 0.f;
            #pragma unroll
            for (int i = 0; i < 16; ++i) {
                float Di = D[i], Pri = Pr[i], Pci = Pc[i];
                db = fmaf(Di,  sw[0 * 256 + i * 16 + j], db);  // W2
                rb = fmaf(Di,  sw[1 * 256 + i * 16 + j], rb);  // W3
                cb = fmaf(Di,  sw[2 * 256 + i * 16 + j], cb);  // W4
                db = fmaf(Pri, sw[3 * 256 + i * 16 + j], db);  // W5
                rb = fmaf(Pri, sw[4 * 256 + i * 16 + j], rb);  // W6
                cb = fmaf(Pri, sw[5 * 256 + i * 16 + j], cb);  // W7
                db = fmaf(Pci, sw[6 * 256 + i * 16 + j], db);  // W8
                rb = fmaf(Pci, sw[7 * 256 + i * 16 + j], rb);  // W9
                cb = fmaf(Pci, sw[8 * 256 + i * 16 + j], cb);  // W10
            }
            diag_b[(size_t)node * DF + j] = db;
            row_b[(size_t)node * DF + j]  = rb;
            col_b[(size_t)node * DF + j]  = cb;
        }
        #pragma unroll
        for (int i = 0; i < 16; ++i) atomicAdd(&spd[i], D[i]);
    }
    __syncthreads();
    if (threadIdx.x < 16) pd_part[blockIdx.x * DF + threadIdx.x] = spd[threadIdx.x];
}

__global__ __launch_bounds__(256) void kS(
    const float* __restrict__ W, const float* __restrict__ bias,
    const float* __restrict__ pa_part, int nblka,
    const float* __restrict__ pd_part, int nblkn,
    float inv_nnz, float inv_n, float* __restrict__ cst)
{
    __shared__ float red[256];
    __shared__ float pa[16], pd[16];
    int t = threadIdx.x;
    int f = t & 15, g = t >> 4;
    float s = 0.f;
    for (int b = g; b < nblka; b += 16) s += pa_part[b * DF + f];
    red[t] = s;
    __syncthreads();
    if (t < 16) {
        float a = 0.f;
        for (int k = t; k < 256; k += 16) a += red[k];
        pa[t] = a * inv_nnz;
    }
    __syncthreads();
    s = 0.f;
    for (int b = g; b < nblkn; b += 16) s += pd_part[b * DF + f];
    red[t] = s;
    __syncthreads();
    if (t < 16) {
        float a = 0.f;
        for (int k = t; k < 256; k += 16) a += red[k];
        pd[t] = a * inv_n;
    }
    __syncthreads();
    if (t < 16) {
        float ds = 0.f, as = 0.f;
        #pragma unroll
        for (int i = 0; i < 16; ++i) {
            float pdi = pd[i], pai = pa[i];
            ds = fmaf(pdi, W[11 * 256 + i * 16 + t], ds);
            ds = fmaf(pai, W[13 * 256 + i * 16 + t], ds);
            as = fmaf(pdi, W[12 * 256 + i * 16 + t], as);
            as = fmaf(pai, W[14 * 256 + i * 16 + t], as);
        }
        cst[t]      = as + bias[t];       // const_all = all_scalar + bias0
        cst[16 + t] = ds + bias[16 + t];  // const_diag = diag_scalar + bias1
    }
}

__global__ __launch_bounds__(256) void kB(
    const float* __restrict__ vals, const int* __restrict__ row,
    const int* __restrict__ col, const float* __restrict__ W,
    const float* __restrict__ row_b, const float* __restrict__ col_b,
    const float* __restrict__ diag_b, const float* __restrict__ cst,
    float* __restrict__ out, int nnz)
{
    __shared__ float w0[256];
    __shared__ float scst[32];
    w0[threadIdx.x] = W[threadIdx.x];
    if (threadIdx.x < 32) scst[threadIdx.x] = cst[threadIdx.x];
    __syncthreads();

    int e = blockIdx.x * blockDim.x + threadIdx.x;
    if (e >= nnz) return;

    const float4* vp = (const float4*)(vals + (size_t)e * DF);
    float4 q0 = vp[0], q1 = vp[1], q2 = vp[2], q3 = vp[3];
    float v[16] = {q0.x, q0.y, q0.z, q0.w, q1.x, q1.y, q1.z, q1.w,
                   q2.x, q2.y, q2.z, q2.w, q3.x, q3.y, q3.z, q3.w};
    int r = row[e], c = col[e];

    float acc[16];
    const float4* rb = (const float4*)(row_b + (size_t)r * DF);
    const float4* cb = (const float4*)(col_b + (size_t)c * DF);
    #pragma unroll
    for (int k = 0; k < 4; ++k) {
        float4 a = rb[k], b = cb[k];
        acc[4 * k + 0] = scst[4 * k + 0] + a.x + b.x;
        acc[4 * k + 1] = scst[4 * k + 1] + a.y + b.y;
        acc[4 * k + 2] = scst[4 * k + 2] + a.z + b.z;
        acc[4 * k + 3] = scst[4 * k + 3] + a.w + b.w;
    }
    if (r == c) {
        const float4* db = (const float4*)(diag_b + (size_t)r * DF);
        #pragma unroll
        for (int k = 0; k < 4; ++k) {
            float4 d = db[k];
            acc[4 * k + 0] += d.x + scst[16 + 4 * k + 0];
            acc[4 * k + 1] += d.y + scst[16 + 4 * k + 1];
            acc[4 * k + 2] += d.z + scst[16 + 4 * k + 2];
            acc[4 * k + 3] += d.w + scst[16 + 4 * k + 3];
        }
    }
    #pragma unroll
    for (int i = 0; i < 16; ++i) {
        float vi = v[i];
        #pragma unroll
        for (int j = 0; j < 16; ++j) acc[j] = fmaf(vi, w0[i * 16 + j], acc[j]);
    }
    float4* op = (float4*)(out + (size_t)e * DF);
    op[0] = make_float4(acc[0], acc[1], acc[2], acc[3]);
    op[1] = make_float4(acc[4], acc[5], acc[6], acc[7]);
    op[2] = make_float4(acc[8], acc[9], acc[10], acc[11]);
    op[3] = make_float4(acc[12], acc[13], acc[14], acc[15]);
}

// 16 lanes per transpose-entry: lane j computes feature j; the 16 scalar
// atomics of one entry land contiguously on one 64B line (proven form).
__global__ __launch_bounds__(256) void kC(
    const float* __restrict__ vals, const int* __restrict__ tin,
    const int* __restrict__ tout, const float* __restrict__ W,
    float* __restrict__ out, int nnzt)
{
    __shared__ float w1[256];
    for (int i = threadIdx.x; i < 256; i += blockDim.x) w1[i] = W[256 + i];
    __syncthreads();

    int gid = blockIdx.x * blockDim.x + threadIdx.x;
    int t = gid >> 4;   // transpose-entry index
    int j = gid & 15;   // feature index
    if (t >= nnzt) return;
    int ei = tin[t], eo = tout[t];

    float vj = vals[(size_t)ei * DF + j];  // 16 lanes -> one 64B line
    float acc = 0.f;
    #pragma unroll
    for (int i = 0; i < 16; ++i) {
        float vi = __shfl(vj, i, 16);      // broadcast v_i within 16-lane group
        acc = fmaf(vi, w1[i * 16 + j], acc);
    }
    atomicAdd(&out[(size_t)eo * DF + j], acc);
}

extern "C" void kernel_launch(void* const* d_in, const int* in_sizes, int n_in,
                              void* d_out, int out_size, void* d_ws, size_t ws_size,
                              hipStream_t stream)
{
    const float* vals    = (const float*)d_in[0];
    const float* weights = (const float*)d_in[1];
    const float* bias    = (const float*)d_in[2];
    const int*   row     = (const int*)d_in[3];
    const int*   col     = (const int*)d_in[4];
    const int*   tin     = (const int*)d_in[5];
    const int*   tout    = (const int*)d_in[6];

    const int nnz  = in_sizes[0] / DF;
    const int nnzt = in_sizes[5];
    const int n    = NNODES;
    const int nblkn = (n + 255) / 256;

    const unsigned long long n34 = (unsigned long long)34 * n;  // floats per replica
    const size_t tail = (size_t)3 * DF * n + (size_t)nblkn * DF + 32;
    const size_t need8 = ((size_t)NXCD * n34 + (size_t)DF * n +
                          (size_t)NBLKA * DF + tail) * sizeof(float);
    const int nrep = (ws_size >= need8) ? NXCD : 1;

    float* ws      = (float*)d_ws;
    float* rep     = ws;
    float* Dsum    = rep + (size_t)nrep * n34;
    float* pa_part = Dsum + (size_t)DF * n;
    float* row_b   = pa_part + (size_t)NBLKA * DF;
    float* col_b   = row_b + (size_t)DF * n;
    float* diag_b  = col_b + (size_t)DF * n;
    float* pd_part = diag_b + (size_t)DF * n;
    float* cst     = pd_part + (size_t)nblkn * DF;

    // zero replicas + Dsum + pa_part
    const size_t zfloats = (size_t)nrep * n34 + (size_t)DF * n + (size_t)NBLKA * DF;
    hipMemsetAsync(ws, 0, zfloats * sizeof(float), stream);

    if (nrep == NXCD) {
        const int P = 4, step = (n + P - 1) / P;   // 25000-node ranges: 3.4MB/XCD slice
        for (int p = 0; p < P; ++p) {
            int lo = p * step;
            int hi = (lo + step < n) ? (lo + step) : n;
            kA2<true><<<NBLKA, 256, 0, stream>>>(vals, row, col, nnz, rep, n34,
                                                 Dsum, pa_part, lo, hi);
        }
    } else {
        kA2<false><<<NBLKA, 256, 0, stream>>>(vals, row, col, nnz, rep, n34,
                                              Dsum, pa_part, 0, n);
    }

    kN<<<nblkn, 256, 0, stream>>>(weights, rep, n34, nrep, Dsum,
                                  row_b, col_b, diag_b, pd_part, n);
    kS<<<1, 256, 0, stream>>>(weights, bias, pa_part, NBLKA, pd_part, nblkn,
                              1.f / (float)nnz, 1.f / (float)n, cst);
    kB<<<(nnz + 255) / 256, 256, 0, stream>>>(vals, row, col, weights, row_b,
                                              col_b, diag_b, cst, (float*)d_out, nnz);

    long long tthreads = (long long)nnzt * DF;
    kC<<<(int)((tthreads + 255) / 256), 256, 0, stream>>>(vals, tin, tout, weights,
                                                          (float*)d_out, nnzt);
}

// Round 12
// 1746.354 us; speedup vs baseline: 1.0893x; 1.0854x over previous
//
#include <hip/hip_runtime.h>

// SparseMatrixEquivariantLayer on MI355X.
//
// Measured law (rounds 0/7/9): every kA variant runs at ~1.2 TB/s of RANDOM
// 64B HBM traffic; global atomics ALWAYS write through 64B per line-touch
// (scope bits don't help: r9 wg-scope L2-resident slices still wrote
// events*64B). So: eliminate atomic scatter entirely.
//
// New pooling pipeline (replaces kA):
//   kBin: counting-scatter entries into 64-node buckets (NB=1563), BOTH keys.
//         Per-block two-pass: LDS histogram -> one global reserve atomic per
//         (block,bucket) -> LDS-cursor scatter of 4B records (e|loc|diag).
//         Perm regions (19.2MB x2) fit aggregate L2 -> writes coalesce.
//   kR3r: one WG per bucket: gather vals[e] (random 64B reads, once), reduce
//         in LDS (sum_row, cnt_row, Dsum, pa partial), write out STREAMING.
//   kR3c: same for columns (sum_col, cnt_col).
// Then the proven round-0 kernels: kN, kS, kB, kC.

#define NNODES 100000
#define DF 16
#define NB 1563          // ceil(100000/64) buckets of 64 nodes
#define BSH 6            // node -> bucket shift
#define CAP 3072         // capacity per bucket (mean 2559, +10 sigma)
#define NBIN 256         // kBin blocks

// ---------------------------------------------------------------- kBin ----
__global__ __launch_bounds__(256) void kBin(
    const int* __restrict__ row, const int* __restrict__ col, int nnz,
    int* __restrict__ fillR, int* __restrict__ fillC,      // NB*16 ints, zeroed
    unsigned int* __restrict__ permR, unsigned int* __restrict__ permC)
{
    __shared__ int hR[NB], hC[NB];   // histogram, then global-base cursor
    for (int i = threadIdx.x; i < NB; i += 256) { hR[i] = 0; hC[i] = 0; }
    __syncthreads();

    const int chunk = (nnz + NBIN - 1) / NBIN;
    const int start = blockIdx.x * chunk;
    const int end   = (start + chunk < nnz) ? (start + chunk) : nnz;

    for (int e = start + threadIdx.x; e < end; e += 256) {
        atomicAdd(&hR[row[e] >> BSH], 1);
        atomicAdd(&hC[col[e] >> BSH], 1);
    }
    __syncthreads();
    for (int b = threadIdx.x; b < NB; b += 256) {
        int nr = hR[b], nc = hC[b];
        hR[b] = nr ? atomicAdd(&fillR[b * 16], nr) : 0;  // reserve global range
        hC[b] = nc ? atomicAdd(&fillC[b * 16], nc) : 0;
    }
    __syncthreads();
    for (int e = start + threadIdx.x; e < end; e += 256) {
        int r = row[e], c = col[e];
        int bR = r >> BSH, bC = c >> BSH;
        unsigned recR = (unsigned)e | ((unsigned)(r & 63) << 22) |
                        ((r == c) ? (1u << 28) : 0u);
        unsigned recC = (unsigned)e | ((unsigned)(c & 63) << 22);
        int pR = atomicAdd(&hR[bR], 1);   // global position within bucket
        int pC = atomicAdd(&hC[bC], 1);
        if (pR < CAP) permR[(size_t)bR * CAP + pR] = recR;
        if (pC < CAP) permC[(size_t)bC * CAP + pC] = recC;
    }
}

// ---------------------------------------------------------------- kR3r ----
__global__ __launch_bounds__(256) void kR3r(
    const float* __restrict__ vals, const unsigned int* __restrict__ permR,
    const int* __restrict__ fillR,
    float* __restrict__ sum_row, float* __restrict__ cnt_row,
    float* __restrict__ Dsum, float* __restrict__ pa_part, int n)
{
    __shared__ float ls[64 * DF], lD[64 * DF], lc[64];
    __shared__ float red[256];
    for (int i = threadIdx.x; i < 64 * DF; i += 256) { ls[i] = 0.f; lD[i] = 0.f; }
    if (threadIdx.x < 64) lc[threadIdx.x] = 0.f;
    __syncthreads();

    const int b = blockIdx.x;
    int nf = fillR[b * 16]; if (nf > CAP) nf = CAP;
    const int f = threadIdx.x & 15;
    const int g = threadIdx.x >> 4;           // 16 entry-groups
    const unsigned int* pb = permR + (size_t)b * CAP;
    float pax = 0.f;
    for (int i = g; i < nf; i += 16) {
        unsigned rec = pb[i];                 // 16 lanes broadcast-load
        int e  = rec & 0x3FFFFF;
        int rl = (rec >> 22) & 63;
        float v = vals[(size_t)e * DF + f];   // one random 64B line per group
        pax += v;
        atomicAdd(&ls[rl * DF + f], v);
        if (rec & (1u << 28)) atomicAdd(&lD[rl * DF + f], v);
        if (f == 0) atomicAdd(&lc[rl], 1.f);
    }
    red[threadIdx.x] = pax;
    __syncthreads();

    const int lo = b << BSH;
    for (int i = threadIdx.x; i < 64 * DF; i += 256) {
        int node = lo + (i >> 4);
        if (node < n) {
            sum_row[(size_t)node * DF + (i & 15)] = ls[i];
            Dsum[(size_t)node * DF + (i & 15)]    = lD[i];
        }
    }
    if (threadIdx.x < 64 && lo + threadIdx.x < n)
        cnt_row[lo + threadIdx.x] = lc[threadIdx.x];
    if (threadIdx.x < 16) {
        float s = 0.f;
        for (int k = threadIdx.x; k < 256; k += 16) s += red[k];
        pa_part[b * DF + threadIdx.x] = s;
    }
}

// ---------------------------------------------------------------- kR3c ----
__global__ __launch_bounds__(256) void kR3c(
    const float* __restrict__ vals, const unsigned int* __restrict__ permC,
    const int* __restrict__ fillC,
    float* __restrict__ sum_col, float* __restrict__ cnt_col, int n)
{
    __shared__ float ls[64 * DF];
    __shared__ float lc[64];
    for (int i = threadIdx.x; i < 64 * DF; i += 256) ls[i] = 0.f;
    if (threadIdx.x < 64) lc[threadIdx.x] = 0.f;
    __syncthreads();

    const int b = blockIdx.x;
    int nf = fillC[b * 16]; if (nf > CAP) nf = CAP;
    const int f = threadIdx.x & 15;
    const int g = threadIdx.x >> 4;
    const unsigned int* pb = permC + (size_t)b * CAP;
    for (int i = g; i < nf; i += 16) {
        unsigned rec = pb[i];
        int e  = rec & 0x3FFFFF;
        int cl = (rec >> 22) & 63;
        float v = vals[(size_t)e * DF + f];
        atomicAdd(&ls[cl * DF + f], v);
        if (f == 0) atomicAdd(&lc[cl], 1.f);
    }
    __syncthreads();

    const int lo = b << BSH;
    for (int i = threadIdx.x; i < 64 * DF; i += 256) {
        int node = lo + (i >> 4);
        if (node < n) sum_col[(size_t)node * DF + (i & 15)] = ls[i];
    }
    if (threadIdx.x < 64 && lo + threadIdx.x < n)
        cnt_col[lo + threadIdx.x] = lc[threadIdx.x];
}

// ------------------------------------------------------------------ kN ----
__global__ __launch_bounds__(256) void kN(
    const float* __restrict__ W,
    const float* __restrict__ sum_row, const float* __restrict__ sum_col,
    const float* __restrict__ Dsum, const float* __restrict__ cnt_row,
    const float* __restrict__ cnt_col,
    float* __restrict__ row_b, float* __restrict__ col_b,
    float* __restrict__ diag_b, float* __restrict__ pd_part, int n)
{
    __shared__ float sw[9 * 256];
    __shared__ float spd[16];
    for (int i = threadIdx.x; i < 9 * 256; i += blockDim.x) sw[i] = W[2 * 256 + i];
    if (threadIdx.x < 16) spd[threadIdx.x] = 0.f;
    __syncthreads();

    int node = blockIdx.x * blockDim.x + threadIdx.x;
    float D[16];
    if (node < n) {
        float Pr[16], Pc[16];
        float cr = fmaxf(cnt_row[node], 1.f);
        float cc = fmaxf(cnt_col[node], 1.f);
        float icr = 1.f / cr, icc = 1.f / cc;
        #pragma unroll
        for (int i = 0; i < 16; ++i) {
            D[i]  = Dsum[(size_t)node * DF + i];
            Pr[i] = sum_row[(size_t)node * DF + i] * icr;
            Pc[i] = sum_col[(size_t)node * DF + i] * icc;
        }
        #pragma unroll
        for (int j = 0; j < 16; ++j) {
            float db = 0.f, rb = 0.f, cb = 0.f;
            #pragma unroll
            for (int i = 0; i < 16; ++i) {
                float Di = D[i], Pri = Pr[i], Pci = Pc[i];
                db = fmaf(Di,  sw[0 * 256 + i * 16 + j], db);  // W2
                rb = fmaf(Di,  sw[1 * 256 + i * 16 + j], rb);  // W3
                cb = fmaf(Di,  sw[2 * 256 + i * 16 + j], cb);  // W4
                db = fmaf(Pri, sw[3 * 256 + i * 16 + j], db);  // W5
                rb = fmaf(Pri, sw[4 * 256 + i * 16 + j], rb);  // W6
                cb = fmaf(Pri, sw[5 * 256 + i * 16 + j], cb);  // W7
                db = fmaf(Pci, sw[6 * 256 + i * 16 + j], db);  // W8
                rb = fmaf(Pci, sw[7 * 256 + i * 16 + j], rb);  // W9
                cb = fmaf(Pci, sw[8 * 256 + i * 16 + j], cb);  // W10
            }
            diag_b[(size_t)node * DF + j] = db;
            row_b[(size_t)node * DF + j]  = rb;
            col_b[(size_t)node * DF + j]  = cb;
        }
        #pragma unroll
        for (int i = 0; i < 16; ++i) atomicAdd(&spd[i], D[i]);
    }
    __syncthreads();
    if (threadIdx.x < 16) pd_part[blockIdx.x * DF + threadIdx.x] = spd[threadIdx.x];
}

// ------------------------------------------------------------------ kS ----
__global__ __launch_bounds__(256) void kS(
    const float* __restrict__ W, const float* __restrict__ bias,
    const float* __restrict__ pa_part, int nblka,
    const float* __restrict__ pd_part, int nblkn,
    float inv_nnz, float inv_n, float* __restrict__ cst)
{
    __shared__ float red[256];
    __shared__ float pa[16], pd[16];
    int t = threadIdx.x;
    int f = t & 15, g = t >> 4;
    float s = 0.f;
    for (int b = g; b < nblka; b += 16) s += pa_part[b * DF + f];
    red[t] = s;
    __syncthreads();
    if (t < 16) {
        float a = 0.f;
        for (int k = t; k < 256; k += 16) a += red[k];
        pa[t] = a * inv_nnz;
    }
    __syncthreads();
    s = 0.f;
    for (int b = g; b < nblkn; b += 16) s += pd_part[b * DF + f];
    red[t] = s;
    __syncthreads();
    if (t < 16) {
        float a = 0.f;
        for (int k = t; k < 256; k += 16) a += red[k];
        pd[t] = a * inv_n;
    }
    __syncthreads();
    if (t < 16) {
        float ds = 0.f, as = 0.f;
        #pragma unroll
        for (int i = 0; i < 16; ++i) {
            float pdi = pd[i], pai = pa[i];
            ds = fmaf(pdi, W[11 * 256 + i * 16 + t], ds);
            ds = fmaf(pai, W[13 * 256 + i * 16 + t], ds);
            as = fmaf(pdi, W[12 * 256 + i * 16 + t], as);
            as = fmaf(pai, W[14 * 256 + i * 16 + t], as);
        }
        cst[t]      = as + bias[t];       // const_all = all_scalar + bias0
        cst[16 + t] = ds + bias[16 + t];  // const_diag = diag_scalar + bias1
    }
}

// ------------------------------------------------------------------ kB ----
__global__ __launch_bounds__(256) void kB(
    const float* __restrict__ vals, const int* __restrict__ row,
    const int* __restrict__ col, const float* __restrict__ W,
    const float* __restrict__ row_b, const float* __restrict__ col_b,
    const float* __restrict__ diag_b, const float* __restrict__ cst,
    float* __restrict__ out, int nnz)
{
    __shared__ float w0[256];
    __shared__ float scst[32];
    w0[threadIdx.x] = W[threadIdx.x];
    if (threadIdx.x < 32) scst[threadIdx.x] = cst[threadIdx.x];
    __syncthreads();

    int e = blockIdx.x * blockDim.x + threadIdx.x;
    if (e >= nnz) return;

    const float4* vp = (const float4*)(vals + (size_t)e * DF);
    float4 q0 = vp[0], q1 = vp[1], q2 = vp[2], q3 = vp[3];
    float v[16] = {q0.x, q0.y, q0.z, q0.w, q1.x, q1.y, q1.z, q1.w,
                   q2.x, q2.y, q2.z, q2.w, q3.x, q3.y, q3.z, q3.w};
    int r = row[e], c = col[e];

    float acc[16];
    const float4* rb = (const float4*)(row_b + (size_t)r * DF);
    const float4* cb = (const float4*)(col_b + (size_t)c * DF);
    #pragma unroll
    for (int k = 0; k < 4; ++k) {
        float4 a = rb[k], b = cb[k];
        acc[4 * k + 0] = scst[4 * k + 0] + a.x + b.x;
        acc[4 * k + 1] = scst[4 * k + 1] + a.y + b.y;
        acc[4 * k + 2] = scst[4 * k + 2] + a.z + b.z;
        acc[4 * k + 3] = scst[4 * k + 3] + a.w + b.w;
    }
    if (r == c) {
        const float4* db = (const float4*)(diag_b + (size_t)r * DF);
        #pragma unroll
        for (int k = 0; k < 4; ++k) {
            float4 d = db[k];
            acc[4 * k + 0] += d.x + scst[16 + 4 * k + 0];
            acc[4 * k + 1] += d.y + scst[16 + 4 * k + 1];
            acc[4 * k + 2] += d.z + scst[16 + 4 * k + 2];
            acc[4 * k + 3] += d.w + scst[16 + 4 * k + 3];
        }
    }
    #pragma unroll
    for (int i = 0; i < 16; ++i) {
        float vi = v[i];
        #pragma unroll
        for (int j = 0; j < 16; ++j) acc[j] = fmaf(vi, w0[i * 16 + j], acc[j]);
    }
    float4* op = (float4*)(out + (size_t)e * DF);
    op[0] = make_float4(acc[0], acc[1], acc[2], acc[3]);
    op[1] = make_float4(acc[4], acc[5], acc[6], acc[7]);
    op[2] = make_float4(acc[8], acc[9], acc[10], acc[11]);
    op[3] = make_float4(acc[12], acc[13], acc[14], acc[15]);
}

// ------------------------------------------------------------------ kC ----
// 16 lanes per transpose-entry: the 16 scalar atomics of one entry land
// contiguously on one 64B line (proven form).
__global__ __launch_bounds__(256) void kC(
    const float* __restrict__ vals, const int* __restrict__ tin,
    const int* __restrict__ tout, const float* __restrict__ W,
    float* __restrict__ out, int nnzt)
{
    __shared__ float w1[256];
    for (int i = threadIdx.x; i < 256; i += blockDim.x) w1[i] = W[256 + i];
    __syncthreads();

    int gid = blockIdx.x * blockDim.x + threadIdx.x;
    int t = gid >> 4;   // transpose-entry index
    int j = gid & 15;   // feature index
    if (t >= nnzt) return;
    int ei = tin[t], eo = tout[t];

    float vj = vals[(size_t)ei * DF + j];  // 16 lanes -> one 64B line
    float acc = 0.f;
    #pragma unroll
    for (int i = 0; i < 16; ++i) {
        float vi = __shfl(vj, i, 16);      // broadcast v_i within 16-lane group
        acc = fmaf(vi, w1[i * 16 + j], acc);
    }
    atomicAdd(&out[(size_t)eo * DF + j], acc);
}

extern "C" void kernel_launch(void* const* d_in, const int* in_sizes, int n_in,
                              void* d_out, int out_size, void* d_ws, size_t ws_size,
                              hipStream_t stream)
{
    const float* vals    = (const float*)d_in[0];
    const float* weights = (const float*)d_in[1];
    const float* bias    = (const float*)d_in[2];
    const int*   row     = (const int*)d_in[3];
    const int*   col     = (const int*)d_in[4];
    const int*   tin     = (const int*)d_in[5];
    const int*   tout    = (const int*)d_in[6];

    const int nnz  = in_sizes[0] / DF;
    const int nnzt = in_sizes[5];
    const int n    = NNODES;
    const int nblkn = (n + 255) / 256;

    // workspace carve (all offsets stay 16B-aligned; total ~78 MB, r9 proved >=134 MB)
    char* w = (char*)d_ws;
    unsigned int* permR = (unsigned int*)w;  w += (size_t)NB * CAP * 4;
    unsigned int* permC = (unsigned int*)w;  w += (size_t)NB * CAP * 4;
    int* fillR = (int*)w;                    w += (size_t)NB * 16 * 4;
    int* fillC = (int*)w;                    w += (size_t)NB * 16 * 4;
    float* sum_row = (float*)w;              w += (size_t)n * DF * 4;
    float* sum_col = (float*)w;              w += (size_t)n * DF * 4;
    float* Dsum    = (float*)w;              w += (size_t)n * DF * 4;
    float* cnt_row = (float*)w;              w += (size_t)n * 4;
    float* cnt_col = (float*)w;              w += (size_t)n * 4;
    float* row_b   = (float*)w;              w += (size_t)n * DF * 4;
    float* col_b   = (float*)w;              w += (size_t)n * DF * 4;
    float* diag_b  = (float*)w;              w += (size_t)n * DF * 4;
    float* pa_part = (float*)w;              w += (size_t)NB * DF * 4;
    float* pd_part = (float*)w;              w += (size_t)nblkn * DF * 4;
    float* cst     = (float*)w;

    // only the fill counters need zeroing (fillR,fillC adjacent)
    hipMemsetAsync(fillR, 0, (size_t)2 * NB * 16 * 4, stream);

    kBin<<<NBIN, 256, 0, stream>>>(row, col, nnz, fillR, fillC, permR, permC);
    kR3r<<<NB, 256, 0, stream>>>(vals, permR, fillR, sum_row, cnt_row, Dsum,
                                 pa_part, n);
    kR3c<<<NB, 256, 0, stream>>>(vals, permC, fillC, sum_col, cnt_col, n);
    kN<<<nblkn, 256, 0, stream>>>(weights, sum_row, sum_col, Dsum, cnt_row,
                                  cnt_col, row_b, col_b, diag_b, pd_part, n);
    kS<<<1, 256, 0, stream>>>(weights, bias, pa_part, NB, pd_part, nblkn,
                              1.f / (float)nnz, 1.f / (float)n, cst);
    kB<<<(nnz + 255) / 256, 256, 0, stream>>>(vals, row, col, weights, row_b,
                                              col_b, diag_b, cst, (float*)d_out, nnz);

    long long tthreads = (long long)nnzt * DF;
    kC<<<(int)((tthreads + 255) / 256), 256, 0, stream>>>(vals, tin, tout, weights,
                                                          (float*)d_out, nnzt);
}